// Round 1
// baseline (1006.617 us; speedup 1.0000x reference)
//
#include <hip/hip_runtime.h>
#include <hip/hip_bf16.h>
#include <stdint.h>

#define VNUM 256
#define DNUM 512
#define BNUM 1024

typedef __attribute__((ext_vector_type(8))) short bf16x8;
typedef __attribute__((ext_vector_type(4))) float f32x4;

// RNE float -> bf16 (bit pattern)
__device__ __forceinline__ uint16_t f2bf(float f) {
    uint32_t u = __float_as_uint(f);
    uint32_t r = (u + 0x7FFFu + ((u >> 16) & 1u)) >> 16;
    return (uint16_t)r;
}

__device__ __forceinline__ void gl_lds16(const void* g, void* l) {
    __builtin_amdgcn_global_load_lds(
        (const __attribute__((address_space(1))) uint32_t*)g,
        (__attribute__((address_space(3))) uint32_t*)l, 16, 0, 0);
}

// ---------------------------------------------------------------- wx = x @ A^T
__global__ __launch_bounds__(256) void wx_kernel(const float* __restrict__ x,
                                                 const float* __restrict__ adj,
                                                 float* __restrict__ wx) {
    __shared__ float xs[64][36];
    __shared__ float as_[64][36];
    const int b0 = blockIdx.x * 64, i0 = blockIdx.y * 64;
    const int t = threadIdx.x;
    const int tx = t & 15, ty = t >> 4;
    const int lr = t >> 2, lk = (t & 3) * 8;
    float c[4][4] = {};
    for (int k0 = 0; k0 < 256; k0 += 32) {
        __syncthreads();
        *(float4*)&xs[lr][lk]      = *(const float4*)&x[(size_t)(b0 + lr) * VNUM + k0 + lk];
        *(float4*)&xs[lr][lk + 4]  = *(const float4*)&x[(size_t)(b0 + lr) * VNUM + k0 + lk + 4];
        *(float4*)&as_[lr][lk]     = *(const float4*)&adj[(size_t)(i0 + lr) * VNUM + k0 + lk];
        *(float4*)&as_[lr][lk + 4] = *(const float4*)&adj[(size_t)(i0 + lr) * VNUM + k0 + lk + 4];
        __syncthreads();
        #pragma unroll
        for (int kk = 0; kk < 32; kk++) {
            float xv[4], av[4];
            #pragma unroll
            for (int a = 0; a < 4; a++) xv[a] = xs[ty + a * 16][kk];
            #pragma unroll
            for (int b = 0; b < 4; b++) av[b] = as_[tx + b * 16][kk];
            #pragma unroll
            for (int a = 0; a < 4; a++)
                #pragma unroll
                for (int b = 0; b < 4; b++) c[a][b] += xv[a] * av[b];
        }
    }
    #pragma unroll
    for (int a = 0; a < 4; a++)
        #pragma unroll
        for (int b = 0; b < 4; b++)
            wx[(size_t)(b0 + ty + a * 16) * VNUM + i0 + tx + b * 16] = c[a][b];
}

// ---------------------------------------------------------------- x -> bf16
__global__ __launch_bounds__(256) void xcvt_kernel(const float* __restrict__ x,
                                                   uint16_t* __restrict__ xbf) {
    const int idx = (blockIdx.x * 256 + threadIdx.x) * 4;
    float4 v = *(const float4*)&x[idx];
    uint32_t p0 = (uint32_t)f2bf(v.x) | ((uint32_t)f2bf(v.y) << 16);
    uint32_t p1 = (uint32_t)f2bf(v.z) | ((uint32_t)f2bf(v.w) << 16);
    *(uint2*)&xbf[idx] = make_uint2(p0, p1);
}

// ---------------------------------------------------------------- GEMM1: h1 = relu(x@W1[:, :256]^T + wx*w1last + b1)
__global__ __launch_bounds__(256) void gemm1_kernel(const uint16_t* __restrict__ xbf,
                                                    const float* __restrict__ wx,
                                                    const float* __restrict__ W1,
                                                    const float* __restrict__ b1,
                                                    uint16_t* __restrict__ h1,
                                                    int ivar_base) {
    const int b0 = blockIdx.x * 128;
    const int d0 = blockIdx.y * 128;
    const int ci = blockIdx.z;
    const int i  = ivar_base + ci;

    __shared__ __align__(16) uint16_t As[128 * 32];
    __shared__ __align__(16) uint16_t Bs[128 * 32];
    __shared__ float wxs[128], w1ls[128], b1s[128];

    const int t = threadIdx.x;
    const int w = t >> 6, l = t & 63;
    const int wm = w >> 1, wn = w & 1;
    const int q = l >> 4, lo = l & 15;

    if (t < 128) {
        wxs[t] = wx[(size_t)(b0 + t) * VNUM + i];
        b1s[t] = b1[(size_t)i * DNUM + d0 + t];
    } else {
        int tt = t - 128;
        w1ls[tt] = W1[((size_t)i * DNUM + d0 + tt) * 257 + 256];
    }

    f32x4 acc[4][4];
    #pragma unroll
    for (int a = 0; a < 4; a++)
        #pragma unroll
        for (int b = 0; b < 4; b++) { f32x4 z = {0.f, 0.f, 0.f, 0.f}; acc[a][b] = z; }

    const int br = t >> 1, kh = t & 1;
    const float* bsrc_row = W1 + ((size_t)i * DNUM + d0 + br) * 257 + kh * 16;
    const int sB = (br >> 1) & 3;
    const int bslot0 = br * 32 + (((kh * 2 + 0) ^ sB) * 8);
    const int bslot1 = br * 32 + (((kh * 2 + 1) ^ sB) * 8);

    for (int k0 = 0; k0 < 256; k0 += 32) {
        __syncthreads();
        #pragma unroll
        for (int p = 0; p < 2; p++) {
            int c  = p * 256 + w * 64 + l;
            int r  = c >> 2, k2 = c & 3;
            int gk2 = k2 ^ ((r >> 1) & 3);
            gl_lds16(xbf + (size_t)(b0 + r) * VNUM + k0 + gk2 * 8,
                     &As[(p * 256 + w * 64) * 8]);
        }
        {
            const float* s = bsrc_row + k0;
            float f[16];
            #pragma unroll
            for (int j = 0; j < 16; j++) f[j] = s[j];
            uint32_t pk[8];
            #pragma unroll
            for (int j = 0; j < 8; j++)
                pk[j] = (uint32_t)f2bf(f[2 * j]) | ((uint32_t)f2bf(f[2 * j + 1]) << 16);
            *(uint4*)&Bs[bslot0] = make_uint4(pk[0], pk[1], pk[2], pk[3]);
            *(uint4*)&Bs[bslot1] = make_uint4(pk[4], pk[5], pk[6], pk[7]);
        }
        __syncthreads();
        bf16x8 af[4], bfr[4];
        #pragma unroll
        for (int mt = 0; mt < 4; mt++) {
            int m = wm * 64 + mt * 16 + lo;
            int slot = q ^ ((m >> 1) & 3);
            af[mt] = *(const bf16x8*)&As[m * 32 + slot * 8];
        }
        #pragma unroll
        for (int nt = 0; nt < 4; nt++) {
            int n = wn * 64 + nt * 16 + lo;
            int slot = q ^ ((n >> 1) & 3);
            bfr[nt] = *(const bf16x8*)&Bs[n * 32 + slot * 8];
        }
        #pragma unroll
        for (int mt = 0; mt < 4; mt++)
            #pragma unroll
            for (int nt = 0; nt < 4; nt++)
                acc[mt][nt] = __builtin_amdgcn_mfma_f32_16x16x32_bf16(af[mt], bfr[nt], acc[mt][nt], 0, 0, 0);
    }

    #pragma unroll
    for (int mt = 0; mt < 4; mt++) {
        #pragma unroll
        for (int reg = 0; reg < 4; reg++) {
            int row = wm * 64 + mt * 16 + q * 4 + reg;
            size_t rowbase = ((size_t)ci * BNUM + b0 + row) * DNUM + d0;
            float wxv = wxs[row];
            #pragma unroll
            for (int nt = 0; nt < 4; nt++) {
                int col = wn * 64 + nt * 16 + lo;
                float v = acc[mt][nt][reg] + wxv * w1ls[col] + b1s[col];
                v = fmaxf(v, 0.f);
                h1[rowbase + col] = f2bf(v);
            }
        }
    }
}

// ---------------------------------------------------------------- GEMM2 + fused layer3
__global__ __launch_bounds__(256) void gemm2_kernel(const uint16_t* __restrict__ h1,
                                                    const float* __restrict__ W2,
                                                    const float* __restrict__ b2,
                                                    const float* __restrict__ W3,
                                                    const float* __restrict__ b3,
                                                    float* __restrict__ out,
                                                    int ivar_base) {
    const int b0 = blockIdx.x * 128;
    const int e0 = blockIdx.y * 128;
    const int ci = blockIdx.z;
    const int i  = ivar_base + ci;

    __shared__ __align__(16) uint16_t As[128 * 32];
    __shared__ __align__(16) uint16_t Bs[128 * 32];
    __shared__ float b2s[128], w3s[128];
    __shared__ float red[2][128];

    const int t = threadIdx.x;
    const int w = t >> 6, l = t & 63;
    const int wm = w >> 1, wn = w & 1;
    const int q = l >> 4, lo = l & 15;

    if (t < 128) b2s[t] = b2[(size_t)i * DNUM + e0 + t];
    else         w3s[t - 128] = W3[(size_t)i * DNUM + e0 + (t - 128)];

    f32x4 acc[4][4];
    #pragma unroll
    for (int a = 0; a < 4; a++)
        #pragma unroll
        for (int b = 0; b < 4; b++) { f32x4 z = {0.f, 0.f, 0.f, 0.f}; acc[a][b] = z; }

    const int br = t >> 1, kh = t & 1;
    const float* bsrc_row = W2 + ((size_t)i * DNUM + e0 + br) * DNUM + kh * 16;
    const int sB = (br >> 1) & 3;
    const int bslot0 = br * 32 + (((kh * 2 + 0) ^ sB) * 8);
    const int bslot1 = br * 32 + (((kh * 2 + 1) ^ sB) * 8);

    const uint16_t* abase = h1 + (size_t)ci * BNUM * DNUM;

    for (int k0 = 0; k0 < 512; k0 += 32) {
        __syncthreads();
        #pragma unroll
        for (int p = 0; p < 2; p++) {
            int c  = p * 256 + w * 64 + l;
            int r  = c >> 2, k2 = c & 3;
            int gk2 = k2 ^ ((r >> 1) & 3);
            gl_lds16(abase + (size_t)(b0 + r) * DNUM + k0 + gk2 * 8,
                     &As[(p * 256 + w * 64) * 8]);
        }
        {
            const float4* s = (const float4*)(bsrc_row + k0);
            float4 fa = s[0], fb = s[1], fc = s[2], fd = s[3];
            uint32_t p0 = (uint32_t)f2bf(fa.x) | ((uint32_t)f2bf(fa.y) << 16);
            uint32_t p1 = (uint32_t)f2bf(fa.z) | ((uint32_t)f2bf(fa.w) << 16);
            uint32_t p2 = (uint32_t)f2bf(fb.x) | ((uint32_t)f2bf(fb.y) << 16);
            uint32_t p3 = (uint32_t)f2bf(fb.z) | ((uint32_t)f2bf(fb.w) << 16);
            uint32_t p4 = (uint32_t)f2bf(fc.x) | ((uint32_t)f2bf(fc.y) << 16);
            uint32_t p5 = (uint32_t)f2bf(fc.z) | ((uint32_t)f2bf(fc.w) << 16);
            uint32_t p6 = (uint32_t)f2bf(fd.x) | ((uint32_t)f2bf(fd.y) << 16);
            uint32_t p7 = (uint32_t)f2bf(fd.z) | ((uint32_t)f2bf(fd.w) << 16);
            *(uint4*)&Bs[bslot0] = make_uint4(p0, p1, p2, p3);
            *(uint4*)&Bs[bslot1] = make_uint4(p4, p5, p6, p7);
        }
        __syncthreads();
        bf16x8 af[4], bfr[4];
        #pragma unroll
        for (int mt = 0; mt < 4; mt++) {
            int m = wm * 64 + mt * 16 + lo;
            int slot = q ^ ((m >> 1) & 3);
            af[mt] = *(const bf16x8*)&As[m * 32 + slot * 8];
        }
        #pragma unroll
        for (int nt = 0; nt < 4; nt++) {
            int n = wn * 64 + nt * 16 + lo;
            int slot = q ^ ((n >> 1) & 3);
            bfr[nt] = *(const bf16x8*)&Bs[n * 32 + slot * 8];
        }
        #pragma unroll
        for (int mt = 0; mt < 4; mt++)
            #pragma unroll
            for (int nt = 0; nt < 4; nt++)
                acc[mt][nt] = __builtin_amdgcn_mfma_f32_16x16x32_bf16(af[mt], bfr[nt], acc[mt][nt], 0, 0, 0);
    }

    // fused layer 3: relu(h2)·W3, reduce over e
    float rs[4][4];
    #pragma unroll
    for (int mt = 0; mt < 4; mt++) {
        #pragma unroll
        for (int reg = 0; reg < 4; reg++) {
            float v = 0.f;
            #pragma unroll
            for (int nt = 0; nt < 4; nt++) {
                int col = wn * 64 + nt * 16 + lo;
                float h = acc[mt][nt][reg] + b2s[col];
                h = fmaxf(h, 0.f);
                v += h * w3s[col];
            }
            v += __shfl_xor(v, 1, 64);
            v += __shfl_xor(v, 2, 64);
            v += __shfl_xor(v, 4, 64);
            v += __shfl_xor(v, 8, 64);
            rs[mt][reg] = v;
        }
    }
    if (lo == 0) {
        #pragma unroll
        for (int mt = 0; mt < 4; mt++)
            #pragma unroll
            for (int reg = 0; reg < 4; reg++) {
                int row = wm * 64 + mt * 16 + q * 4 + reg;
                red[wn][row] = rs[mt][reg];
            }
    }
    __syncthreads();
    if (t < 128) {
        float v = red[0][t] + red[1][t];
        if (e0 == 0) v += b3[i];
        atomicAdd(&out[(size_t)(b0 + t) * VNUM + i], v);
    }
}

// ----------------------------------------------------------------
extern "C" void kernel_launch(void* const* d_in, const int* in_sizes, int n_in,
                              void* d_out, int out_size, void* d_ws, size_t ws_size,
                              hipStream_t stream) {
    const float* x   = (const float*)d_in[0];
    const float* adj = (const float*)d_in[1];
    const float* W1  = (const float*)d_in[2];
    const float* b1  = (const float*)d_in[3];
    const float* W2  = (const float*)d_in[4];
    const float* b2  = (const float*)d_in[5];
    const float* W3  = (const float*)d_in[6];
    const float* b3  = (const float*)d_in[7];
    float* out = (float*)d_out;

    char* ws = (char*)d_ws;
    float*    wx  = (float*)ws;                                  // 1 MB
    uint16_t* xbf = (uint16_t*)(ws + (1 << 20));                 // 0.5 MB
    uint16_t* h1  = (uint16_t*)(ws + (1 << 20) + (1 << 19));     // CV MB

    const size_t fixed = (1 << 20) + (1 << 19);
    int CV = 64;
    while (CV > 1 && ws_size < fixed + (size_t)CV * BNUM * DNUM * 2) CV >>= 1;

    hipMemsetAsync(d_out, 0, (size_t)BNUM * VNUM * sizeof(float), stream);
    wx_kernel<<<dim3(16, 4), 256, 0, stream>>>(x, adj, wx);
    xcvt_kernel<<<256, 256, 0, stream>>>(x, xbf);
    for (int c = 0; c < VNUM; c += CV) {
        gemm1_kernel<<<dim3(8, 4, CV), 256, 0, stream>>>(xbf, wx, W1, b1, h1, c);
        gemm2_kernel<<<dim3(8, 4, CV), 256, 0, stream>>>(h1, W2, b2, W3, b3, out, c);
    }
}

// Round 2
// 891.286 us; speedup vs baseline: 1.1294x; 1.1294x over previous
//
#include <hip/hip_runtime.h>
#include <hip/hip_bf16.h>
#include <stdint.h>

#define VNUM 256
#define DNUM 512
#define BNUM 1024

typedef __attribute__((ext_vector_type(8))) short bf16x8;
typedef __attribute__((ext_vector_type(4))) float f32x4;

// RNE float -> bf16 (bit pattern)
__device__ __forceinline__ uint16_t f2bf(float f) {
    uint32_t u = __float_as_uint(f);
    uint32_t r = (u + 0x7FFFu + ((u >> 16) & 1u)) >> 16;
    return (uint16_t)r;
}

__device__ __forceinline__ void gl_lds16(const void* g, void* l) {
    __builtin_amdgcn_global_load_lds(
        (const __attribute__((address_space(1))) uint32_t*)g,
        (__attribute__((address_space(3))) uint32_t*)l, 16, 0, 0);
}

// ---------------------------------------------------------------- wx = x @ A^T
__global__ __launch_bounds__(256) void wx_kernel(const float* __restrict__ x,
                                                 const float* __restrict__ adj,
                                                 float* __restrict__ wx) {
    __shared__ float xs[64][36];
    __shared__ float as_[64][36];
    const int b0 = blockIdx.x * 64, i0 = blockIdx.y * 64;
    const int t = threadIdx.x;
    const int tx = t & 15, ty = t >> 4;
    const int lr = t >> 2, lk = (t & 3) * 8;
    float c[4][4] = {};
    for (int k0 = 0; k0 < 256; k0 += 32) {
        __syncthreads();
        *(float4*)&xs[lr][lk]      = *(const float4*)&x[(size_t)(b0 + lr) * VNUM + k0 + lk];
        *(float4*)&xs[lr][lk + 4]  = *(const float4*)&x[(size_t)(b0 + lr) * VNUM + k0 + lk + 4];
        *(float4*)&as_[lr][lk]     = *(const float4*)&adj[(size_t)(i0 + lr) * VNUM + k0 + lk];
        *(float4*)&as_[lr][lk + 4] = *(const float4*)&adj[(size_t)(i0 + lr) * VNUM + k0 + lk + 4];
        __syncthreads();
        #pragma unroll
        for (int kk = 0; kk < 32; kk++) {
            float xv[4], av[4];
            #pragma unroll
            for (int a = 0; a < 4; a++) xv[a] = xs[ty + a * 16][kk];
            #pragma unroll
            for (int b = 0; b < 4; b++) av[b] = as_[tx + b * 16][kk];
            #pragma unroll
            for (int a = 0; a < 4; a++)
                #pragma unroll
                for (int b = 0; b < 4; b++) c[a][b] += xv[a] * av[b];
        }
    }
    #pragma unroll
    for (int a = 0; a < 4; a++)
        #pragma unroll
        for (int b = 0; b < 4; b++)
            wx[(size_t)(b0 + ty + a * 16) * VNUM + i0 + tx + b * 16] = c[a][b];
}

// ---------------------------------------------------------------- x -> bf16
__global__ __launch_bounds__(256) void xcvt_kernel(const float* __restrict__ x,
                                                   uint16_t* __restrict__ xbf) {
    const int idx = (blockIdx.x * 256 + threadIdx.x) * 4;
    float4 v = *(const float4*)&x[idx];
    uint32_t p0 = (uint32_t)f2bf(v.x) | ((uint32_t)f2bf(v.y) << 16);
    uint32_t p1 = (uint32_t)f2bf(v.z) | ((uint32_t)f2bf(v.w) << 16);
    *(uint2*)&xbf[idx] = make_uint2(p0, p1);
}

// ---------------------------------------------------------------- W1 -> bf16 repack [V][D][256] + fp32 last col
// one thread per (row, k) output element, k in [0,256)
__global__ __launch_bounds__(256) void w1cvt_kernel(const float* __restrict__ W1,
                                                    uint16_t* __restrict__ W1bf,
                                                    float* __restrict__ w1last) {
    const size_t idx = (size_t)blockIdx.x * 256 + threadIdx.x;
    const size_t row = idx >> 8;          // i*512 + d
    const int    k   = (int)(idx & 255);
    const float* src = W1 + row * 257;
    W1bf[idx] = f2bf(src[k]);
    if (k == 0) w1last[row] = src[256];
}

// ---------------------------------------------------------------- W2 -> bf16 (same layout)
__global__ __launch_bounds__(256) void w2cvt_kernel(const float* __restrict__ W2,
                                                    uint16_t* __restrict__ W2bf) {
    const size_t idx = ((size_t)blockIdx.x * 256 + threadIdx.x) * 4;
    float4 v = *(const float4*)&W2[idx];
    uint32_t p0 = (uint32_t)f2bf(v.x) | ((uint32_t)f2bf(v.y) << 16);
    uint32_t p1 = (uint32_t)f2bf(v.z) | ((uint32_t)f2bf(v.w) << 16);
    *(uint2*)&W2bf[idx] = make_uint2(p0, p1);
}

// ---------------------------------------------------------------- GEMM1: h1 = relu(x@W1[:, :256]^T + wx*w1last + b1)
__global__ __launch_bounds__(256) void gemm1_kernel(const uint16_t* __restrict__ xbf,
                                                    const float* __restrict__ wx,
                                                    const uint16_t* __restrict__ W1bf,
                                                    const float* __restrict__ w1last,
                                                    const float* __restrict__ b1,
                                                    uint16_t* __restrict__ h1) {
    const int b0 = blockIdx.x * 128;
    const int d0 = blockIdx.y * 128;
    const int ci = blockIdx.z;
    const int i  = ci;

    __shared__ __align__(16) uint16_t As[128 * 32];
    __shared__ __align__(16) uint16_t Bs[128 * 32];
    __shared__ float wxs[128], w1ls[128], b1s[128];

    const int t = threadIdx.x;
    const int w = t >> 6, l = t & 63;
    const int wm = w >> 1, wn = w & 1;
    const int q = l >> 4, lo = l & 15;

    if (t < 128) {
        wxs[t] = wx[(size_t)(b0 + t) * VNUM + i];
        b1s[t] = b1[(size_t)i * DNUM + d0 + t];
    } else {
        int tt = t - 128;
        w1ls[tt] = w1last[(size_t)i * DNUM + d0 + tt];
    }

    f32x4 acc[4][4];
    #pragma unroll
    for (int a = 0; a < 4; a++)
        #pragma unroll
        for (int b = 0; b < 4; b++) { f32x4 z = {0.f, 0.f, 0.f, 0.f}; acc[a][b] = z; }

    // staging geometry (identical for A and B): 128 rows x 32 k of bf16 = 512
    // 16B-chunks; chunk c -> row r=c>>2, stored k2=c&3 holds global gk2=k2^((r>>1)&3)
    const int c_  = w * 64 + l;
    const int rA  = c_ >> 2,        kA = (c_ & 3) ^ ((rA >> 2) & 0);  // placeholder (computed below)

    const uint16_t* Abase = xbf;                                   // [B][256]
    const uint16_t* Bbase = W1bf + (size_t)i * DNUM * 256;         // [D][256]

    for (int k0 = 0; k0 < 256; k0 += 32) {
        __syncthreads();
        #pragma unroll
        for (int p = 0; p < 2; p++) {
            int c  = p * 256 + w * 64 + l;
            int r  = c >> 2, k2 = c & 3;
            int gk2 = k2 ^ ((r >> 1) & 3);
            gl_lds16(Abase + (size_t)(b0 + r) * 256 + k0 + gk2 * 8,
                     &As[(p * 256 + w * 64) * 8]);
        }
        #pragma unroll
        for (int p = 0; p < 2; p++) {
            int c  = p * 256 + w * 64 + l;
            int r  = c >> 2, k2 = c & 3;
            int gk2 = k2 ^ ((r >> 1) & 3);
            gl_lds16(Bbase + (size_t)(d0 + r) * 256 + k0 + gk2 * 8,
                     &Bs[(p * 256 + w * 64) * 8]);
        }
        __syncthreads();
        bf16x8 af[4], bfr[4];
        #pragma unroll
        for (int mt = 0; mt < 4; mt++) {
            int m = wm * 64 + mt * 16 + lo;
            int slot = q ^ ((m >> 1) & 3);
            af[mt] = *(const bf16x8*)&As[m * 32 + slot * 8];
        }
        #pragma unroll
        for (int nt = 0; nt < 4; nt++) {
            int n = wn * 64 + nt * 16 + lo;
            int slot = q ^ ((n >> 1) & 3);
            bfr[nt] = *(const bf16x8*)&Bs[n * 32 + slot * 8];
        }
        #pragma unroll
        for (int mt = 0; mt < 4; mt++)
            #pragma unroll
            for (int nt = 0; nt < 4; nt++)
                acc[mt][nt] = __builtin_amdgcn_mfma_f32_16x16x32_bf16(af[mt], bfr[nt], acc[mt][nt], 0, 0, 0);
    }
    (void)rA; (void)kA;

    #pragma unroll
    for (int mt = 0; mt < 4; mt++) {
        #pragma unroll
        for (int reg = 0; reg < 4; reg++) {
            int row = wm * 64 + mt * 16 + q * 4 + reg;
            size_t rowbase = ((size_t)ci * BNUM + b0 + row) * DNUM + d0;
            float wxv = wxs[row];
            #pragma unroll
            for (int nt = 0; nt < 4; nt++) {
                int col = wn * 64 + nt * 16 + lo;
                float v = acc[mt][nt][reg] + wxv * w1ls[col] + b1s[col];
                v = fmaxf(v, 0.f);
                h1[rowbase + col] = f2bf(v);
            }
        }
    }
}

// ---------------------------------------------------------------- GEMM2 + fused layer3
__global__ __launch_bounds__(256) void gemm2_kernel(const uint16_t* __restrict__ h1,
                                                    const uint16_t* __restrict__ W2bf,
                                                    const float* __restrict__ b2,
                                                    const float* __restrict__ W3,
                                                    const float* __restrict__ b3,
                                                    float* __restrict__ out) {
    const int b0 = blockIdx.x * 128;
    const int e0 = blockIdx.y * 128;
    const int ci = blockIdx.z;
    const int i  = ci;

    __shared__ __align__(16) uint16_t As[128 * 32];
    __shared__ __align__(16) uint16_t Bs[128 * 32];
    __shared__ float b2s[128], w3s[128];
    __shared__ float red[2][128];

    const int t = threadIdx.x;
    const int w = t >> 6, l = t & 63;
    const int wm = w >> 1, wn = w & 1;
    const int q = l >> 4, lo = l & 15;

    if (t < 128) b2s[t] = b2[(size_t)i * DNUM + e0 + t];
    else         w3s[t - 128] = W3[(size_t)i * DNUM + e0 + (t - 128)];

    f32x4 acc[4][4];
    #pragma unroll
    for (int a = 0; a < 4; a++)
        #pragma unroll
        for (int b = 0; b < 4; b++) { f32x4 z = {0.f, 0.f, 0.f, 0.f}; acc[a][b] = z; }

    const uint16_t* Abase = h1 + (size_t)ci * BNUM * DNUM;               // [B][512]
    const uint16_t* Bbase = W2bf + (size_t)i * DNUM * DNUM;              // [E][512]

    for (int k0 = 0; k0 < 512; k0 += 32) {
        __syncthreads();
        #pragma unroll
        for (int p = 0; p < 2; p++) {
            int c  = p * 256 + w * 64 + l;
            int r  = c >> 2, k2 = c & 3;
            int gk2 = k2 ^ ((r >> 1) & 3);
            gl_lds16(Abase + (size_t)(b0 + r) * DNUM + k0 + gk2 * 8,
                     &As[(p * 256 + w * 64) * 8]);
        }
        #pragma unroll
        for (int p = 0; p < 2; p++) {
            int c  = p * 256 + w * 64 + l;
            int r  = c >> 2, k2 = c & 3;
            int gk2 = k2 ^ ((r >> 1) & 3);
            gl_lds16(Bbase + (size_t)(e0 + r) * DNUM + k0 + gk2 * 8,
                     &Bs[(p * 256 + w * 64) * 8]);
        }
        __syncthreads();
        bf16x8 af[4], bfr[4];
        #pragma unroll
        for (int mt = 0; mt < 4; mt++) {
            int m = wm * 64 + mt * 16 + lo;
            int slot = q ^ ((m >> 1) & 3);
            af[mt] = *(const bf16x8*)&As[m * 32 + slot * 8];
        }
        #pragma unroll
        for (int nt = 0; nt < 4; nt++) {
            int n = wn * 64 + nt * 16 + lo;
            int slot = q ^ ((n >> 1) & 3);
            bfr[nt] = *(const bf16x8*)&Bs[n * 32 + slot * 8];
        }
        #pragma unroll
        for (int mt = 0; mt < 4; mt++)
            #pragma unroll
            for (int nt = 0; nt < 4; nt++)
                acc[mt][nt] = __builtin_amdgcn_mfma_f32_16x16x32_bf16(af[mt], bfr[nt], acc[mt][nt], 0, 0, 0);
    }

    // fused layer 3: relu(h2)·W3, reduce over e
    float rs[4][4];
    #pragma unroll
    for (int mt = 0; mt < 4; mt++) {
        #pragma unroll
        for (int reg = 0; reg < 4; reg++) {
            float v = 0.f;
            #pragma unroll
            for (int nt = 0; nt < 4; nt++) {
                int col = wn * 64 + nt * 16 + lo;
                float h = acc[mt][nt][reg] + b2s[col];
                h = fmaxf(h, 0.f);
                v += h * w3s[col];
            }
            v += __shfl_xor(v, 1, 64);
            v += __shfl_xor(v, 2, 64);
            v += __shfl_xor(v, 4, 64);
            v += __shfl_xor(v, 8, 64);
            rs[mt][reg] = v;
        }
    }
    if (lo == 0) {
        #pragma unroll
        for (int mt = 0; mt < 4; mt++)
            #pragma unroll
            for (int reg = 0; reg < 4; reg++) {
                int row = wm * 64 + mt * 16 + q * 4 + reg;
                red[wn][row] = rs[mt][reg];
            }
    }
    __syncthreads();
    if (t < 128) {
        float v = red[0][t] + red[1][t];
        if (e0 == 0) v += b3[i];
        atomicAdd(&out[(size_t)(b0 + t) * VNUM + i], v);
    }
}

// ----------------------------------------------------------------
extern "C" void kernel_launch(void* const* d_in, const int* in_sizes, int n_in,
                              void* d_out, int out_size, void* d_ws, size_t ws_size,
                              hipStream_t stream) {
    const float* x   = (const float*)d_in[0];
    const float* adj = (const float*)d_in[1];
    const float* W1  = (const float*)d_in[2];
    const float* b1  = (const float*)d_in[3];
    const float* W2  = (const float*)d_in[4];
    const float* b2  = (const float*)d_in[5];
    const float* W3  = (const float*)d_in[6];
    const float* b3  = (const float*)d_in[7];
    float* out = (float*)d_out;

    // workspace layout (ws_size observed ~1 GiB; total need ~472 MB)
    char* ws = (char*)d_ws;
    float*    wx     = (float*)ws;                                   // 1 MB
    uint16_t* xbf    = (uint16_t*)(ws + (1 << 20));                  // 0.5 MB
    float*    w1last = (float*)(ws + (1 << 20) + (1 << 19));         // 0.5 MB
    char*     p      = ws + (2 << 20);
    uint16_t* W1bf   = (uint16_t*)p;                                 // 67.1 MB
    p += (size_t)VNUM * DNUM * 256 * 2;
    uint16_t* W2bf   = (uint16_t*)p;                                 // 134.2 MB
    p += (size_t)VNUM * DNUM * DNUM * 2;
    uint16_t* h1     = (uint16_t*)p;                                 // 268.4 MB

    hipMemsetAsync(d_out, 0, (size_t)BNUM * VNUM * sizeof(float), stream);
    wx_kernel<<<dim3(16, 4), 256, 0, stream>>>(x, adj, wx);
    xcvt_kernel<<<256, 256, 0, stream>>>(x, xbf);
    w1cvt_kernel<<<(VNUM * DNUM * 256) / 256, 256, 0, stream>>>(W1, W1bf, w1last);
    w2cvt_kernel<<<(VNUM * DNUM * DNUM) / (4 * 256), 256, 0, stream>>>(W2, W2bf);
    gemm1_kernel<<<dim3(8, 4, VNUM), 256, 0, stream>>>(xbf, wx, W1bf, w1last, b1, h1);
    gemm2_kernel<<<dim3(8, 4, VNUM), 256, 0, stream>>>(h1, W2bf, b2, W3, b3, out);
}